// Round 3
// baseline (1209.320 us; speedup 1.0000x reference)
//
#include <hip/hip_runtime.h>

// VectorQuantizer: z (65536 x 512 f32), codebook (16 x 512 f32)
// out = [z_q (65536*512 f32)] [indices as f32 (65536)] [vq_loss (1)]
//
// Key correctness insight (round 1/2 post-mortem): the reference computes
// distances = |z|^2 - 2 z.C^T + |c|^2 in FLOAT32, where |z|^2 ~ 512 makes the
// final values quantized at ulp(512) ~ 6e-5. A handful of rows TIE exactly in
// f32, and argmin tie-breaks to the FIRST index. Computing the true (f64 or
// offset-free f32) argmin resolves those ties differently -> absmax 5 on the
// index output in both prior rounds. Fix: compute A,B,C exactly in f64, then
// replicate the reference's f32 op sequence d = fl32(fl32(A-2B)+C) and argmin
// over the f32 values with first-index tie-break.

constexpr int D      = 512;
constexpr int D4     = D / 4;      // 128 float4 per row
constexpr int K      = 16;
constexpr int BLOCK  = 256;
constexpr int WAVES  = BLOCK / 64;             // 4
constexpr int ROWS_PER_WAVE  = 4;
constexpr int ROWS_PER_BLOCK = WAVES * ROWS_PER_WAVE;  // 16
constexpr int GRID   = 2048;

__global__ void __launch_bounds__(BLOCK, 4) vq_kernel(
    const float* __restrict__ z, const float* __restrict__ cb,
    float* __restrict__ zq, float* __restrict__ idx_out,
    float* __restrict__ loss_out, int n_rows, float loss_scale)
{
    __shared__ float  cb_lds[K * D];       // 32 KB
    __shared__ double cnorm_lds[K];
    __shared__ float  wave_loss[WAVES];

    const int tid  = threadIdx.x;
    const int lane = tid & 63;
    const int wave = tid >> 6;
    const int sub  = lane >> 4;            // which of the wave's 4 rows
    const int sl   = lane & 15;            // column-group within row

    // ---- stage codebook in LDS (coalesced float4) ----
    const float4* cb4 = reinterpret_cast<const float4*>(cb);
    float4*       cl4 = reinterpret_cast<float4*>(cb_lds);
    #pragma unroll
    for (int i = 0; i < (K * D4) / BLOCK; ++i)           // 8 iters
        cl4[i * BLOCK + tid] = cb4[i * BLOCK + tid];
    __syncthreads();

    // ---- per-code squared norms in f64 (16 threads per code) ----
    {
        const int k = tid >> 4;
        const int s = tid & 15;
        double acc = 0.0;
        #pragma unroll
        for (int i = 0; i < 8; ++i) {
            float4 c = cl4[k * D4 + i * 16 + s];
            acc += (double)c.x * (double)c.x + (double)c.y * (double)c.y
                 + (double)c.z * (double)c.z + (double)c.w * (double)c.w;
        }
        #pragma unroll
        for (int m = 1; m < 16; m <<= 1)
            acc += __shfl_xor(acc, m, 64);
        if (s == 0) cnorm_lds[k] = acc;
    }
    __syncthreads();
    // lane sl owns code sl after the reduce-scatter; pre-round C to f32
    const float my_cnorm32 = (float)cnorm_lds[sl];

    const float4* z4  = reinterpret_cast<const float4*>(z);
    float4*       zq4 = reinterpret_cast<float4*>(zq);

    float lp = 0.f;   // loss partial (f32 is plenty for the loss output)

    const int n_tiles = n_rows / ROWS_PER_BLOCK;
    for (int tile = blockIdx.x; tile < n_tiles; tile += GRID) {
        const int row = tile * ROWS_PER_BLOCK + wave * ROWS_PER_WAVE + sub;
        const long long rb = (long long)row * D4;

        // ---- load this lane's 32 z elements (8 x float4, coalesced) ----
        float4 zr[8];
        #pragma unroll
        for (int i = 0; i < 8; ++i)
            zr[i] = z4[rb + i * 16 + sl];

        // ---- A = |z|^2 in f64: per-lane partial, then 16-lane all-reduce ----
        double A = 0.0;
        #pragma unroll
        for (int i = 0; i < 8; ++i) {
            A += (double)zr[i].x * (double)zr[i].x + (double)zr[i].y * (double)zr[i].y
               + (double)zr[i].z * (double)zr[i].z + (double)zr[i].w * (double)zr[i].w;
        }
        #pragma unroll
        for (int m = 1; m < 16; m <<= 1)
            A += __shfl_xor(A, m, 64);
        const float A32 = (float)A;

        // ---- 16 partial dot products in f64 vs LDS codebook ----
        double p[K];
        #pragma unroll
        for (int k = 0; k < K; ++k) p[k] = 0.0;
        #pragma unroll
        for (int i = 0; i < 8; ++i) {
            const double zx = (double)zr[i].x, zy = (double)zr[i].y;
            const double zz = (double)zr[i].z, zw = (double)zr[i].w;
            #pragma unroll
            for (int k = 0; k < K; ++k) {
                float4 c = cl4[k * D4 + i * 16 + sl];
                p[k] = fma((double)c.x, zx,
                       fma((double)c.y, zy,
                       fma((double)c.z, zz,
                       fma((double)c.w, zw, p[k]))));
            }
        }

        // ---- butterfly reduce-scatter over the 16-lane group:
        //      afterwards lane (sub*16 + c) holds the FULL dot for code c ----
        #pragma unroll
        for (int b = 0; b < 4; ++b) {
            const int m     = 1 << b;
            const int mybit = (lane >> b) & 1;
            const int cnt   = 16 >> (b + 1);
            #pragma unroll
            for (int c = 0; c < cnt; ++c) {
                double send = mybit ? p[2 * c] : p[2 * c + 1];  // value partner keeps
                double recv = __shfl_xor(send, m, 64);
                p[c] = (mybit ? p[2 * c + 1] : p[2 * c]) + recv;
            }
        }

        // ---- replicate the reference's f32 distance arithmetic:
        //      d = fl32( fl32(A32 - 2*B32) + C32 )  (2*B32 is exact) ----
        const float B32 = (float)p[0];
        float bd = (A32 - 2.0f * B32) + my_cnorm32;
        int   bk = sl;

        // ---- f32 argmin over 16 codes, first-index tie-break (== np.argmin) ----
        #pragma unroll
        for (int b = 0; b < 4; ++b) {
            float od = __shfl_xor(bd, 1 << b, 64);
            int   ok = __shfl_xor(bk, 1 << b, 64);
            if (od < bd || (od == bd && ok < bk)) { bd = od; bk = ok; }
        }
        if (sl == 0) idx_out[row] = (float)bk;

        // ---- gather codebook row -> z_q, accumulate loss (f32) ----
        #pragma unroll
        for (int i = 0; i < 8; ++i) {
            float4 c = cl4[bk * D4 + i * 16 + sl];
            zq4[rb + i * 16 + sl] = c;
            float dx = zr[i].x - c.x, dy = zr[i].y - c.y;
            float dz = zr[i].z - c.z, dw = zr[i].w - c.w;
            lp += dx * dx + dy * dy + dz * dz + dw * dw;
        }
    }

    // ---- loss reduction: wave butterfly -> LDS -> one float atomic per block ----
    #pragma unroll
    for (int m = 1; m < 64; m <<= 1)
        lp += __shfl_xor(lp, m, 64);
    if (lane == 0) wave_loss[wave] = lp;
    __syncthreads();
    if (tid == 0) {
        float s = 0.f;
        #pragma unroll
        for (int w = 0; w < WAVES; ++w) s += wave_loss[w];
        atomicAdd(loss_out, s * loss_scale);
    }
}

extern "C" void kernel_launch(void* const* d_in, const int* in_sizes, int n_in,
                              void* d_out, int out_size, void* d_ws, size_t ws_size,
                              hipStream_t stream) {
    const float* z  = (const float*)d_in[0];
    const float* cb = (const float*)d_in[1];

    const int n_elems = in_sizes[0];        // 33554432
    const int n_rows  = n_elems / D;        // 65536

    float* zq   = (float*)d_out;
    float* idx  = zq + n_elems;
    float* loss = idx + n_rows;

    // loss element is atomically accumulated -> must start at 0 (d_out is poisoned)
    hipMemsetAsync((void*)loss, 0, sizeof(float), stream);

    const float loss_scale = 1.25f / (float)n_elems;
    vq_kernel<<<GRID, BLOCK, 0, stream>>>(z, cb, zq, idx, loss, n_rows, loss_scale);
}

// Round 5
// 865.449 us; speedup vs baseline: 1.3973x; 1.3973x over previous
//
#include <hip/hip_runtime.h>

// VectorQuantizer: z (65536 x 512 f32), codebook (16 x 512 f32)
// out = [z_q (65536*512 f32)] [indices as f32 (65536)] [vq_loss (1)]
//
// Numerics (verified round 3): compute A=|z|^2, B=z.c, C=|c|^2 exactly in f64,
// round each to f32, then replicate the reference's f32 op sequence
// d = fl32(fl32(A - 2B) + C) and argmin with first-index tie-break. This
// reproduces the reference's f32 tie set (ulp(512) ~ 6e-5 grid).
//
// Perf (round-3 post-mortem): double p[16] + float4 zr[8] live together
// spilled to scratch -> 2.8 GB HBM traffic, 1068 us. Restructured: codes
// processed in 4 chunks of 4 -> only 4 f64 accumulators live (8 VGPRs),
// no spills, traffic back to ~0.26 GB.

constexpr int D      = 512;
constexpr int D4     = D / 4;      // 128 float4 per row
constexpr int K      = 16;
constexpr int BLOCK  = 256;
constexpr int WAVES  = BLOCK / 64;             // 4
constexpr int ROWS_PER_WAVE  = 4;
constexpr int ROWS_PER_BLOCK = WAVES * ROWS_PER_WAVE;  // 16
constexpr int GRID   = 2048;

__global__ void __launch_bounds__(BLOCK) vq_kernel(
    const float* __restrict__ z, const float* __restrict__ cb,
    float* __restrict__ zq, float* __restrict__ idx_out,
    float* __restrict__ loss_out, int n_rows, float loss_scale)
{
    __shared__ float cb_lds[K * D];        // 32 KB
    __shared__ float cnorm_lds[K];         // f32-rounded f64 norms
    __shared__ float wave_loss[WAVES];

    const int tid  = threadIdx.x;
    const int lane = tid & 63;
    const int wave = tid >> 6;
    const int sub  = lane >> 4;            // which of the wave's 4 rows
    const int sl   = lane & 15;            // column-group within row

    // ---- stage codebook in LDS (coalesced float4) ----
    const float4* cb4 = reinterpret_cast<const float4*>(cb);
    float4*       cl4 = reinterpret_cast<float4*>(cb_lds);
    #pragma unroll
    for (int i = 0; i < (K * D4) / BLOCK; ++i)           // 8 iters
        cl4[i * BLOCK + tid] = cb4[i * BLOCK + tid];
    __syncthreads();

    // ---- per-code squared norms in f64, rounded to f32 (16 threads/code) ----
    {
        const int k = tid >> 4;
        const int s = tid & 15;
        double acc = 0.0;
        #pragma unroll
        for (int i = 0; i < 8; ++i) {
            float4 c = cl4[k * D4 + i * 16 + s];
            acc += (double)c.x * (double)c.x + (double)c.y * (double)c.y
                 + (double)c.z * (double)c.z + (double)c.w * (double)c.w;
        }
        #pragma unroll
        for (int m = 1; m < 16; m <<= 1)
            acc += __shfl_xor(acc, m, 64);
        if (s == 0) cnorm_lds[k] = (float)acc;
    }
    __syncthreads();

    // this lane's 4 owned codes are {4c + (sl&3)}, c = 0..3
    const int base_k = sl & 3;
    float cn[4];
    #pragma unroll
    for (int c = 0; c < 4; ++c) cn[c] = cnorm_lds[4 * c + base_k];

    const float4* z4  = reinterpret_cast<const float4*>(z);
    float4*       zq4 = reinterpret_cast<float4*>(zq);

    float lp = 0.f;   // loss partial (f32 is plenty for the loss output)

    const int n_tiles = n_rows / ROWS_PER_BLOCK;
    for (int tile = blockIdx.x; tile < n_tiles; tile += GRID) {
        const int row = tile * ROWS_PER_BLOCK + wave * ROWS_PER_WAVE + sub;
        const long long rb = (long long)row * D4;

        // ---- load this lane's 32 z elements (8 x float4, coalesced) ----
        float4 zr[8];
        #pragma unroll
        for (int i = 0; i < 8; ++i)
            zr[i] = z4[rb + i * 16 + sl];

        // ---- A = |z|^2 in f64: per-lane partial + 16-lane all-reduce ----
        double A = 0.0;
        #pragma unroll
        for (int i = 0; i < 8; ++i) {
            A += (double)zr[i].x * (double)zr[i].x + (double)zr[i].y * (double)zr[i].y
               + (double)zr[i].z * (double)zr[i].z + (double)zr[i].w * (double)zr[i].w;
        }
        #pragma unroll
        for (int m = 1; m < 16; m <<= 1)
            A += __shfl_xor(A, m, 64);
        const float A32 = (float)A;

        // ---- B = z . c_k in f64, 4 codes per chunk (low register pressure) ----
        float B32[4];
        #pragma unroll
        for (int c = 0; c < 4; ++c) {
            double a0 = 0.0, a1 = 0.0, a2 = 0.0, a3 = 0.0;
            #pragma unroll
            for (int i = 0; i < 8; ++i) {
                const int    idx = (4 * c) * D4 + i * 16 + sl;
                const double zx = (double)zr[i].x, zy = (double)zr[i].y;
                const double zz = (double)zr[i].z, zw = (double)zr[i].w;
                float4 c0 = cl4[idx];
                float4 c1 = cl4[idx + D4];
                float4 c2 = cl4[idx + 2 * D4];
                float4 c3 = cl4[idx + 3 * D4];
                a0 = fma((double)c0.x, zx, fma((double)c0.y, zy, fma((double)c0.z, zz, fma((double)c0.w, zw, a0))));
                a1 = fma((double)c1.x, zx, fma((double)c1.y, zy, fma((double)c1.z, zz, fma((double)c1.w, zw, a1))));
                a2 = fma((double)c2.x, zx, fma((double)c2.y, zy, fma((double)c2.z, zz, fma((double)c2.w, zw, a2))));
                a3 = fma((double)c3.x, zx, fma((double)c3.y, zy, fma((double)c3.z, zz, fma((double)c3.w, zw, a3))));
            }
            // reduce-scatter over lane bits 0,1: lane keeps code 4c + (lane&3)
            {
                const int mb0 = lane & 1;
                double s0 = mb0 ? a0 : a1;
                double s1 = mb0 ? a2 : a3;
                double r0 = __shfl_xor(s0, 1, 64);
                double r1 = __shfl_xor(s1, 1, 64);
                double t0 = (mb0 ? a1 : a0) + r0;
                double t1 = (mb0 ? a3 : a2) + r1;
                const int mb1 = (lane >> 1) & 1;
                double s2 = mb1 ? t0 : t1;
                double r2 = __shfl_xor(s2, 2, 64);
                double u  = (mb1 ? t1 : t0) + r2;
                // complete the row sum over lane bits 2,3 (all-reduce)
                u += __shfl_xor(u, 4, 64);
                u += __shfl_xor(u, 8, 64);
                B32[c] = (float)u;
            }
        }

        // ---- reference's f32 distance sequence + argmin (first-index ties) ----
        float bd = (A32 - 2.0f * B32[0]) + cn[0];
        int   bk = base_k;
        #pragma unroll
        for (int c = 1; c < 4; ++c) {
            float d = (A32 - 2.0f * B32[c]) + cn[c];
            if (d < bd) { bd = d; bk = 4 * c + base_k; }   // strict < keeps lowest code
        }
        #pragma unroll
        for (int b = 0; b < 2; ++b) {                      // codes replicated over bits 2,3
            float od = __shfl_xor(bd, 1 << b, 64);
            int   ok = __shfl_xor(bk, 1 << b, 64);
            if (od < bd || (od == bd && ok < bk)) { bd = od; bk = ok; }
        }
        if (sl == 0) idx_out[row] = (float)bk;

        // ---- gather codebook row -> z_q, accumulate loss (f32) ----
        #pragma unroll
        for (int i = 0; i < 8; ++i) {
            float4 c = cl4[bk * D4 + i * 16 + sl];
            zq4[rb + i * 16 + sl] = c;
            float dx = zr[i].x - c.x, dy = zr[i].y - c.y;
            float dz = zr[i].z - c.z, dw = zr[i].w - c.w;
            lp += dx * dx + dy * dy + dz * dz + dw * dw;
        }
    }

    // ---- loss reduction: wave butterfly -> LDS -> one float atomic per block ----
    #pragma unroll
    for (int m = 1; m < 64; m <<= 1)
        lp += __shfl_xor(lp, m, 64);
    if (lane == 0) wave_loss[wave] = lp;
    __syncthreads();
    if (tid == 0) {
        float s = 0.f;
        #pragma unroll
        for (int w = 0; w < WAVES; ++w) s += wave_loss[w];
        atomicAdd(loss_out, s * loss_scale);
    }
}

extern "C" void kernel_launch(void* const* d_in, const int* in_sizes, int n_in,
                              void* d_out, int out_size, void* d_ws, size_t ws_size,
                              hipStream_t stream) {
    const float* z  = (const float*)d_in[0];
    const float* cb = (const float*)d_in[1];

    const int n_elems = in_sizes[0];        // 33554432
    const int n_rows  = n_elems / D;        // 65536

    float* zq   = (float*)d_out;
    float* idx  = zq + n_elems;
    float* loss = idx + n_rows;

    // loss element is atomically accumulated -> must start at 0 (d_out is poisoned)
    hipMemsetAsync((void*)loss, 0, sizeof(float), stream);

    const float loss_scale = 1.25f / (float)n_elems;
    vq_kernel<<<GRID, BLOCK, 0, stream>>>(z, cb, zq, idx, loss, n_rows, loss_scale);
}

// Round 6
// 326.891 us; speedup vs baseline: 3.6995x; 2.6475x over previous
//
#include <hip/hip_runtime.h>

// VectorQuantizer: z (65536 x 512 f32), codebook (16 x 512 f32)
// out = [z_q (65536*512 f32)] [indices as f32 (65536)] [vq_loss (1)]
//
// Numerics (verified round 3): compute A=|z|^2, B=z.c, C=|c|^2 exactly in f64,
// round each to f32, then replicate the reference's f32 op sequence
// d = fl32(fl32(A - 2B) + C) and argmin with first-index tie-break. This
// reproduces the reference's f32 tie set (ulp(512) ~ 6e-5 grid). DO NOT
// change the numerics.
//
// Perf history:
//  r3: double p[16] live -> spill, 2.8 GB HBM, 1068 us.
//  r5: chunked-4 but full unroll of 4x8 LDS-load loop -> compiler hoisted
//      ~128 VGPRs of codebook loads, VGPR=256 + residual spill, 1.18 GB, 719 us.
//  r6 (this): #pragma unroll 1 on the inner FMA loop keeps ~80 VGPRs live;
//      __launch_bounds__(256,4) caps allocation at 128 -> no scratch,
//      4 blocks/CU (LDS-capped), ~0.27 GB traffic.

constexpr int D      = 512;
constexpr int D4     = D / 4;      // 128 float4 per row
constexpr int K      = 16;
constexpr int BLOCK  = 256;
constexpr int WAVES  = BLOCK / 64;             // 4
constexpr int ROWS_PER_WAVE  = 4;
constexpr int ROWS_PER_BLOCK = WAVES * ROWS_PER_WAVE;  // 16
constexpr int GRID   = 2048;

__global__ void __launch_bounds__(BLOCK, 4) vq_kernel(
    const float* __restrict__ z, const float* __restrict__ cb,
    float* __restrict__ zq, float* __restrict__ idx_out,
    float* __restrict__ loss_out, int n_rows, float loss_scale)
{
    __shared__ float cb_lds[K * D];        // 32 KB
    __shared__ float cnorm_lds[K];         // f32-rounded f64 norms
    __shared__ float wave_loss[WAVES];

    const int tid  = threadIdx.x;
    const int lane = tid & 63;
    const int wave = tid >> 6;
    const int sub  = lane >> 4;            // which of the wave's 4 rows
    const int sl   = lane & 15;            // column-group within row

    // ---- stage codebook in LDS (coalesced float4) ----
    const float4* cb4 = reinterpret_cast<const float4*>(cb);
    float4*       cl4 = reinterpret_cast<float4*>(cb_lds);
    #pragma unroll
    for (int i = 0; i < (K * D4) / BLOCK; ++i)           // 8 iters
        cl4[i * BLOCK + tid] = cb4[i * BLOCK + tid];
    __syncthreads();

    // ---- per-code squared norms in f64, rounded to f32 (16 threads/code) ----
    {
        const int k = tid >> 4;
        const int s = tid & 15;
        double acc = 0.0;
        #pragma unroll
        for (int i = 0; i < 8; ++i) {
            float4 c = cl4[k * D4 + i * 16 + s];
            acc += (double)c.x * (double)c.x + (double)c.y * (double)c.y
                 + (double)c.z * (double)c.z + (double)c.w * (double)c.w;
        }
        #pragma unroll
        for (int m = 1; m < 16; m <<= 1)
            acc += __shfl_xor(acc, m, 64);
        if (s == 0) cnorm_lds[k] = (float)acc;
    }
    __syncthreads();

    // this lane's 4 owned codes are {4c + (sl&3)}, c = 0..3
    const int base_k = sl & 3;
    float cn[4];
    #pragma unroll
    for (int c = 0; c < 4; ++c) cn[c] = cnorm_lds[4 * c + base_k];

    const float4* z4  = reinterpret_cast<const float4*>(z);
    float4*       zq4 = reinterpret_cast<float4*>(zq);

    float lp = 0.f;   // loss partial (f32 is plenty for the loss output)

    const int n_tiles = n_rows / ROWS_PER_BLOCK;
    for (int tile = blockIdx.x; tile < n_tiles; tile += GRID) {
        const int row = tile * ROWS_PER_BLOCK + wave * ROWS_PER_WAVE + sub;
        const long long rb = (long long)row * D4;

        // ---- load this lane's 32 z elements (8 x float4, coalesced) ----
        float4 zr[8];
        #pragma unroll
        for (int i = 0; i < 8; ++i)
            zr[i] = z4[rb + i * 16 + sl];

        // ---- A = |z|^2 in f64: per-lane partial + 16-lane all-reduce ----
        double A = 0.0;
        #pragma unroll
        for (int i = 0; i < 8; ++i) {
            A += (double)zr[i].x * (double)zr[i].x + (double)zr[i].y * (double)zr[i].y
               + (double)zr[i].z * (double)zr[i].z + (double)zr[i].w * (double)zr[i].w;
        }
        #pragma unroll
        for (int m = 1; m < 16; m <<= 1)
            A += __shfl_xor(A, m, 64);
        const float A32 = (float)A;

        // ---- B = z . c_k in f64, 4 codes per chunk; inner loop NOT unrolled
        //      to keep register liveness low (r5 post-mortem) ----
        float B32[4];
        #pragma unroll
        for (int c = 0; c < 4; ++c) {
            double a0 = 0.0, a1 = 0.0, a2 = 0.0, a3 = 0.0;
            #pragma unroll 1
            for (int i = 0; i < 8; ++i) {
                const int    idx = (4 * c) * D4 + i * 16 + sl;
                const double zx = (double)zr[i].x, zy = (double)zr[i].y;
                const double zz = (double)zr[i].z, zw = (double)zr[i].w;
                float4 c0 = cl4[idx];
                float4 c1 = cl4[idx + D4];
                float4 c2 = cl4[idx + 2 * D4];
                float4 c3 = cl4[idx + 3 * D4];
                a0 = fma((double)c0.x, zx, fma((double)c0.y, zy, fma((double)c0.z, zz, fma((double)c0.w, zw, a0))));
                a1 = fma((double)c1.x, zx, fma((double)c1.y, zy, fma((double)c1.z, zz, fma((double)c1.w, zw, a1))));
                a2 = fma((double)c2.x, zx, fma((double)c2.y, zy, fma((double)c2.z, zz, fma((double)c2.w, zw, a2))));
                a3 = fma((double)c3.x, zx, fma((double)c3.y, zy, fma((double)c3.z, zz, fma((double)c3.w, zw, a3))));
            }
            // reduce-scatter over lane bits 0,1: lane keeps code 4c + (lane&3)
            {
                const int mb0 = lane & 1;
                double s0 = mb0 ? a0 : a1;
                double s1 = mb0 ? a2 : a3;
                double r0 = __shfl_xor(s0, 1, 64);
                double r1 = __shfl_xor(s1, 1, 64);
                double t0 = (mb0 ? a1 : a0) + r0;
                double t1 = (mb0 ? a3 : a2) + r1;
                const int mb1 = (lane >> 1) & 1;
                double s2 = mb1 ? t0 : t1;
                double r2 = __shfl_xor(s2, 2, 64);
                double u  = (mb1 ? t1 : t0) + r2;
                // complete the row sum over lane bits 2,3 (all-reduce)
                u += __shfl_xor(u, 4, 64);
                u += __shfl_xor(u, 8, 64);
                B32[c] = (float)u;
            }
        }

        // ---- reference's f32 distance sequence + argmin (first-index ties) ----
        float bd = (A32 - 2.0f * B32[0]) + cn[0];
        int   bk = base_k;
        #pragma unroll
        for (int c = 1; c < 4; ++c) {
            float d = (A32 - 2.0f * B32[c]) + cn[c];
            if (d < bd) { bd = d; bk = 4 * c + base_k; }   // strict < keeps lowest code
        }
        #pragma unroll
        for (int b = 0; b < 2; ++b) {                      // codes replicated over bits 2,3
            float od = __shfl_xor(bd, 1 << b, 64);
            int   ok = __shfl_xor(bk, 1 << b, 64);
            if (od < bd || (od == bd && ok < bk)) { bd = od; bk = ok; }
        }
        if (sl == 0) idx_out[row] = (float)bk;

        // ---- gather codebook row -> z_q, accumulate loss (f32) ----
        #pragma unroll
        for (int i = 0; i < 8; ++i) {
            float4 c = cl4[bk * D4 + i * 16 + sl];
            zq4[rb + i * 16 + sl] = c;
            float dx = zr[i].x - c.x, dy = zr[i].y - c.y;
            float dz = zr[i].z - c.z, dw = zr[i].w - c.w;
            lp += dx * dx + dy * dy + dz * dz + dw * dw;
        }
    }

    // ---- loss reduction: wave butterfly -> LDS -> one float atomic per block ----
    #pragma unroll
    for (int m = 1; m < 64; m <<= 1)
        lp += __shfl_xor(lp, m, 64);
    if (lane == 0) wave_loss[wave] = lp;
    __syncthreads();
    if (tid == 0) {
        float s = 0.f;
        #pragma unroll
        for (int w = 0; w < WAVES; ++w) s += wave_loss[w];
        atomicAdd(loss_out, s * loss_scale);
    }
}

extern "C" void kernel_launch(void* const* d_in, const int* in_sizes, int n_in,
                              void* d_out, int out_size, void* d_ws, size_t ws_size,
                              hipStream_t stream) {
    const float* z  = (const float*)d_in[0];
    const float* cb = (const float*)d_in[1];

    const int n_elems = in_sizes[0];        // 33554432
    const int n_rows  = n_elems / D;        // 65536

    float* zq   = (float*)d_out;
    float* idx  = zq + n_elems;
    float* loss = idx + n_rows;

    // loss element is atomically accumulated -> must start at 0 (d_out is poisoned)
    hipMemsetAsync((void*)loss, 0, sizeof(float), stream);

    const float loss_scale = 1.25f / (float)n_elems;
    vq_kernel<<<GRID, BLOCK, 0, stream>>>(z, cb, zq, idx, loss, n_rows, loss_scale);
}